// Round 5
// baseline (507.702 us; speedup 1.0000x reference)
//
#include <hip/hip_runtime.h>
#include <math.h>

#define NPTS 262144
#define D 128
#define KC 1024

typedef __bf16 bf16x8 __attribute__((ext_vector_type(8)));
typedef float floatx4 __attribute__((ext_vector_type(4)));

// async global->LDS, 16B per lane. LDS dest must be wave-uniform base (+lane*16 in HW).
__device__ __forceinline__ void async_copy16(const void* g, void* l) {
    __builtin_amdgcn_global_load_lds(
        (const __attribute__((address_space(1))) void*)g,
        (__attribute__((address_space(3))) void*)l, 16, 0, 0);
}

// ---------------- centroid norms + bf16 convert ----------------
__global__ void cc_kernel(const float* __restrict__ C, float* __restrict__ CC,
                          unsigned short* __restrict__ Cbf) {
    const int row  = blockIdx.x;
    const int lane = threadIdx.x;
    float2 v = *(const float2*)(C + (size_t)row * D + lane * 2);
    __bf16 b0 = (__bf16)v.x, b1 = (__bf16)v.y;
    unsigned short u0, u1;
    __builtin_memcpy(&u0, &b0, 2);
    __builtin_memcpy(&u1, &b1, 2);
    ((ushort2*)Cbf)[(size_t)row * 64 + lane] = make_ushort2(u0, u1);
    float s = fmaf(v.x, v.x, v.y * v.y);
#pragma unroll
    for (int m = 1; m < 64; m <<= 1) s += __shfl_xor(s, m, 64);
    if (lane == 0) CC[row] = s;
}

// ---------------- assignment: LDS-staged bf16 MFMA + packed argmin ------
// 256 thr = 4 waves, BM=256 pts/block. Centroids staged in 16 double-
// buffered 16KB chunks via global_load_lds w=16, XOR-swizzled both sides.
// Packed argmin: step index (6 bits) in the low mantissa of the running
// min (v_and_or_b32 + v_min_f32 per candidate).
// __launch_bounds__(256,4): gfx950 unified VGPR/AGPR file -- rocprof's
// VGPR_Count=84 was arch-only; at (256,2) the compiler parked acc copies
// in AGPRs pushing TOTAL past the 170-reg 2-waves/SIMD boundary (occupancy
// stuck at 26%). Post-packed-argmin live set ~124 <= 128, so a 128-total
// budget now fits WITHOUT the round-2 spills (that version had bk[][]+
// 4-wide b frags, live ~148). Tripwire: FETCH_SIZE >> 68 MB => spilled.
#define BM 256
#define KCH 64             // centroids per LDS chunk
#define NCH (KC / KCH)     // 16 chunks
#define CHB (KCH * D * 2)  // 16384 bytes per chunk

__device__ __forceinline__ void stage_chunk(const unsigned short* __restrict__ Cbf,
                                            unsigned short* buf, int chunk,
                                            int t, int w) {
    const char* gbase = (const char*)Cbf + (size_t)chunk * CHB;
    char* lbase = (char*)buf + w * 1024;   // wave-uniform; HW adds lane*16
#pragma unroll
    for (int it = 0; it < CHB / 4096; it++) {
        const int a   = it * 4096 + t * 16;     // linear byte offset in chunk
        const int row = a >> 8;                 // 0..63 (256 B per row)
        const int src = (row << 8) | ((a & 255) ^ ((row & 7) << 4));
        async_copy16(gbase + src, lbase + it * 4096);
    }
}

__global__ __launch_bounds__(256, 4) void assign_kernel(
    const float* __restrict__ X,
    const unsigned short* __restrict__ Cbf,
    const float* __restrict__ CC,
    int* __restrict__ y_hat,
    float* __restrict__ inertia)
{
    __shared__ __align__(16) unsigned short Bs[2][KCH * D];  // 2 x 16 KB
    __shared__ float CCs[KC];   // 4 KB
    __shared__ float xxs[BM];   // 1 KB

    const int t    = threadIdx.x;
    const int w    = t >> 6;
    const int lane = t & 63;
    const int m16  = lane & 15;
    const int quad = lane >> 4;
    const int pbase = blockIdx.x * BM;

    for (int i = t; i < KC; i += 256) CCs[i] = CC[i];

    // kick off chunk-0 staging early: overlaps the X/afrag HBM phase
    stage_chunk(Cbf, Bs[0], 0, t, w);

    // ---- A fragments (bf16) + exact fp32 ||x||^2 ----
    bf16x8 afrag[4][4];
#pragma unroll
    for (int mt = 0; mt < 4; mt++) {
        const int p = pbase + w * 64 + mt * 16 + m16;
        const float* xr = X + (size_t)p * D;
        float xp = 0.f;
#pragma unroll
        for (int ks = 0; ks < 4; ks++) {
            const int d0 = ks * 32 + quad * 8;
            float4 u0 = *(const float4*)(xr + d0);
            float4 u1 = *(const float4*)(xr + d0 + 4);
            xp = fmaf(u0.x, u0.x, xp); xp = fmaf(u0.y, u0.y, xp);
            xp = fmaf(u0.z, u0.z, xp); xp = fmaf(u0.w, u0.w, xp);
            xp = fmaf(u1.x, u1.x, xp); xp = fmaf(u1.y, u1.y, xp);
            xp = fmaf(u1.z, u1.z, xp); xp = fmaf(u1.w, u1.w, xp);
            bf16x8 f;
            f[0] = (__bf16)u0.x; f[1] = (__bf16)u0.y; f[2] = (__bf16)u0.z; f[3] = (__bf16)u0.w;
            f[4] = (__bf16)u1.x; f[5] = (__bf16)u1.y; f[6] = (__bf16)u1.z; f[7] = (__bf16)u1.w;
            afrag[mt][ks] = f;
        }
        xp += __shfl_xor(xp, 16, 64);
        xp += __shfl_xor(xp, 32, 64);
        if (quad == 0) xxs[w * 64 + mt * 16 + m16] = xp;
    }

    // packed running min: value in high bits, global step index in low 6
    float best[4][4];
#pragma unroll
    for (int mt = 0; mt < 4; mt++)
#pragma unroll
        for (int r = 0; r < 4; r++) best[mt][r] = 3.4e38f;

    __syncthreads();   // chunk-0 staged (vmcnt drained), CCs ready

    for (int ch = 0; ch < NCH; ch++) {
        // prefetch next chunk into the other buffer (drained by end-barrier)
        if (ch + 1 < NCH) stage_chunk(Cbf, Bs[(ch + 1) & 1], ch + 1, t, w);

        const char* bufc = (const char*)Bs[ch & 1];
#pragma unroll
        for (int s = 0; s < KCH / 16; s++) {
            const int row  = s * 16 + m16;
            const int rswz = (row & 7) << 4;
            const char* rb = bufc + row * 256;

            floatx4 accs[4];
#pragma unroll
            for (int mt = 0; mt < 4; mt++) accs[mt] = (floatx4){0.f, 0.f, 0.f, 0.f};

            // two half-passes of (2 ds_read + 8 MFMA): bounds b-frag pressure
#pragma unroll
            for (int kh = 0; kh < 2; kh++) {
                bf16x8 b0 = *(const bf16x8*)(rb + ((quad * 16 + (kh * 2 + 0) * 64) ^ rswz));
                bf16x8 b1 = *(const bf16x8*)(rb + ((quad * 16 + (kh * 2 + 1) * 64) ^ rswz));
#pragma unroll
                for (int mt = 0; mt < 4; mt++)
                    accs[mt] = __builtin_amdgcn_mfma_f32_16x16x32_bf16(
                        afrag[mt][kh * 2 + 0], b0, accs[mt], 0, 0, 0);
#pragma unroll
                for (int mt = 0; mt < 4; mt++)
                    accs[mt] = __builtin_amdgcn_mfma_f32_16x16x32_bf16(
                        afrag[mt][kh * 2 + 1], b1, accs[mt], 0, 0, 0);
            }

            const int g = ch * (KCH / 16) + s;   // global step 0..63
            const float ccv = CCs[g * 16 + m16];
#pragma unroll
            for (int mt = 0; mt < 4; mt++)
#pragma unroll
                for (int r = 0; r < 4; r++) {
                    float d2 = fmaf(-2.f, accs[mt][r], ccv);
                    unsigned ub = (__float_as_uint(d2) & ~63u) | (unsigned)g;
                    best[mt][r] = fminf(best[mt][r], __uint_as_float(ub));
                }
        }
        if (ch + 1 < NCH) __syncthreads();  // drains prefetch; protects buffer reuse
    }

    // ---- unpack + cross-lane argmin over the 16 columns + write ----
    float part = 0.f;
#pragma unroll
    for (int mt = 0; mt < 4; mt++)
#pragma unroll
        for (int r = 0; r < 4; r++) {
            const unsigned ub = __float_as_uint(best[mt][r]);
            int   k = (int)(ub & 63u) * 16 + m16;
            float b = __uint_as_float(ub & ~63u);
#pragma unroll
            for (int m = 1; m < 16; m <<= 1) {
                float ob = __shfl_xor(b, m, 64);
                int   ok = __shfl_xor(k, m, 64);
                if (ob < b || (ob == b && ok < k)) { b = ob; k = ok; }
            }
            if (m16 == 0) {
                const int row = quad * 4 + r;
                const int p = pbase + w * 64 + mt * 16 + row;
                y_hat[p] = k;
                const float xx = xxs[w * 64 + mt * 16 + row];
                part += sqrtf(fmaxf(xx + b, 0.f));
            }
        }
#pragma unroll
    for (int m = 1; m < 64; m <<= 1) part += __shfl_xor(part, m, 64);
    if (lane == 0) atomicAdd(inertia, part);
}

// ---------------- histogram: 64 blocks, LDS bins, sparse flush ----------
__global__ void hist_kernel(const int* __restrict__ y_hat, int* __restrict__ counts) {
    __shared__ int h[KC];
    for (int i = threadIdx.x; i < KC; i += 256) h[i] = 0;
    __syncthreads();
    for (int i = blockIdx.x * 256 + threadIdx.x; i < NPTS; i += gridDim.x * 256)
        atomicAdd(&h[y_hat[i]], 1);
    __syncthreads();
    for (int i = threadIdx.x; i < KC; i += 256) {
        int v = h[i];
        if (v) atomicAdd(&counts[i], v);
    }
}

// ---------------- exclusive scan ----------------
__global__ void scan_kernel(const int* __restrict__ counts, int* __restrict__ cursor) {
    __shared__ int tmp[KC];
    int t = threadIdx.x;
    tmp[t] = counts[t];
    __syncthreads();
    for (int off = 1; off < KC; off <<= 1) {
        int v = tmp[t];
        int add = (t >= off) ? tmp[t - off] : 0;
        __syncthreads();
        tmp[t] = v + add;
        __syncthreads();
    }
    cursor[t] = (t == 0) ? 0 : tmp[t - 1];
}

// ---------------- scatter: LDS-rank, one cursor bump per (block,bin) -----
#define SPB 2048   // points per scatter block
__global__ __launch_bounds__(256) void scatter_kernel(
    const int* __restrict__ y_hat,
    int* __restrict__ cursor,
    int* __restrict__ order)
{
    __shared__ int h[KC];
    const int t = threadIdx.x;
    const int base_i = blockIdx.x * SPB;
    for (int i = t; i < KC; i += 256) h[i] = 0;
    __syncthreads();
    int myk[SPB / 256], myr[SPB / 256];
#pragma unroll
    for (int j = 0; j < SPB / 256; j++) {
        int k = y_hat[base_i + j * 256 + t];
        myk[j] = k;
        myr[j] = atomicAdd(&h[k], 1);
    }
    __syncthreads();
    for (int b = t; b < KC; b += 256) {
        int c = h[b];
        if (c) h[b] = atomicAdd(&cursor[b], c);   // reuse h[] as base[]
    }
    __syncthreads();
#pragma unroll
    for (int j = 0; j < SPB / 256; j++)
        order[h[myk[j]] + myr[j]] = base_i + j * 256 + t;
}

// ---------------- segmented reduction: depth-4 prefetch ----------------
#define PPB 256
__global__ __launch_bounds__(256) void segsum_kernel(
    const float* __restrict__ X, const float* __restrict__ W,
    const int* __restrict__ order, const int* __restrict__ y_hat,
    float* __restrict__ w_sum, float* __restrict__ xw_sum)
{
    __shared__ int ps[PPB];
    __shared__ int kk[PPB];
    const int t = threadIdx.x;
    const int i0 = blockIdx.x * PPB;
    {
        int p = order[i0 + t];
        ps[t] = p;
        kk[t] = y_hat[p];
    }
    __syncthreads();

    const int d = t & 127;
    const int g = t >> 7;    // half: points g, g+2, ...

    float xs[4], wv[4];
#pragma unroll
    for (int j = 0; j < 4; j++) {
        int p = ps[g + 2 * j];
        xs[j] = X[(size_t)p * D + d];
        wv[j] = W[(size_t)p * D + d];
    }

    float wacc = 0.f, xwacc = 0.f;
    int cur = -1;

#pragma unroll 4
    for (int i = g; i < PPB; i += 2) {
        float xn = 0.f, wn = 0.f;
        if (i + 8 < PPB) {
            int p = ps[i + 8];
            xn = X[(size_t)p * D + d];
            wn = W[(size_t)p * D + d];
        }
        int k = kk[i];
        if (k != cur) {
            if (cur >= 0) {
                atomicAdd(&w_sum[(size_t)cur * D + d], wacc);
                atomicAdd(&xw_sum[(size_t)cur * D + d], xwacc);
            }
            cur = k; wacc = 0.f; xwacc = 0.f;
        }
        wacc += wv[0];
        xwacc = fmaf(xs[0], wv[0], xwacc);
        xs[0] = xs[1]; xs[1] = xs[2]; xs[2] = xs[3]; xs[3] = xn;
        wv[0] = wv[1]; wv[1] = wv[2]; wv[2] = wv[3]; wv[3] = wn;
    }
    if (cur >= 0) {
        atomicAdd(&w_sum[(size_t)cur * D + d], wacc);
        atomicAdd(&xw_sum[(size_t)cur * D + d], xwacc);
    }
}

extern "C" void kernel_launch(void* const* d_in, const int* in_sizes, int n_in,
                              void* d_out, int out_size, void* d_ws, size_t ws_size,
                              hipStream_t stream) {
    const float* X = (const float*)d_in[0];
    const float* W = (const float*)d_in[1];
    const float* C = (const float*)d_in[2];

    float* out     = (float*)d_out;
    float* inertia = out;
    float* w_sum   = out + 1;
    float* xw_sum  = out + 1 + KC * D;

    int*   y_hat  = (int*)d_ws;
    int*   order  = y_hat + NPTS;
    int*   counts = order + NPTS;
    int*   cursor = counts + KC;
    float* CC     = (float*)(cursor + KC);
    unsigned short* Cbf = (unsigned short*)(CC + KC);   // 1024*128 bf16, 16B-aligned

    hipMemsetAsync(d_out, 0, (size_t)out_size * sizeof(float), stream);
    hipMemsetAsync(counts, 0, KC * sizeof(int), stream);

    cc_kernel<<<KC, 64, 0, stream>>>(C, CC, Cbf);
    assign_kernel<<<NPTS / BM, 256, 0, stream>>>(X, Cbf, CC, y_hat, inertia);
    hist_kernel<<<64, 256, 0, stream>>>(y_hat, counts);
    scan_kernel<<<1, KC, 0, stream>>>(counts, cursor);
    scatter_kernel<<<NPTS / SPB, 256, 0, stream>>>(y_hat, cursor, order);
    segsum_kernel<<<NPTS / PPB, 256, 0, stream>>>(X, W, order, y_hat, w_sum, xw_sum);
}

// Round 6
// 451.044 us; speedup vs baseline: 1.1256x; 1.1256x over previous
//
#include <hip/hip_runtime.h>
#include <math.h>

#define NPTS 262144
#define D 128
#define KC 1024

typedef __bf16 bf16x8 __attribute__((ext_vector_type(8)));
typedef float floatx4 __attribute__((ext_vector_type(4)));

// async global->LDS, 16B per lane. LDS dest must be wave-uniform base (+lane*16 in HW).
__device__ __forceinline__ void async_copy16(const void* g, void* l) {
    __builtin_amdgcn_global_load_lds(
        (const __attribute__((address_space(1))) void*)g,
        (__attribute__((address_space(3))) void*)l, 16, 0, 0);
}

// ---------------- centroid norms + bf16 convert ----------------
__global__ void cc_kernel(const float* __restrict__ C, float* __restrict__ CC,
                          unsigned short* __restrict__ Cbf) {
    const int row  = blockIdx.x;
    const int lane = threadIdx.x;
    float2 v = *(const float2*)(C + (size_t)row * D + lane * 2);
    __bf16 b0 = (__bf16)v.x, b1 = (__bf16)v.y;
    unsigned short u0, u1;
    __builtin_memcpy(&u0, &b0, 2);
    __builtin_memcpy(&u1, &b1, 2);
    ((ushort2*)Cbf)[(size_t)row * 64 + lane] = make_ushort2(u0, u1);
    float s = fmaf(v.x, v.x, v.y * v.y);
#pragma unroll
    for (int m = 1; m < 64; m <<= 1) s += __shfl_xor(s, m, 64);
    if (lane == 0) CC[row] = s;
}

// ---------------- assignment: LDS-staged bf16 MFMA + packed argmin ------
// 512 thr = 8 waves, BM=256 pts/block, mt=2 (32 pts/wave). Round 2/5
// post-mortem: with mt=4 the afrag alone is 64 VGPR and the true live set
// ~140 -- no launch_bounds can reach 4 waves/SIMD without spilling
// (FETCH 270..876 MB disasters). mt=2 halves per-wave state (~85 live)
// so __launch_bounds__(512,4) fits a 128-reg budget spill-free ->
// 4 waves/SIMD, 2 blocks/CU. Block-level HBM/L2 traffic unchanged; LDS
// read traffic doubles (2 GB aggregate ~ +15us at 69 TB/s) -- paid for
// by 2x latency hiding. Tripwire: FETCH_SIZE >> 68 MB => spilled.
#define BM 256
#define NW 8               // waves per block
#define MT 2               // 16-row point tiles per wave
#define KCH 64             // centroids per LDS chunk
#define NCH (KC / KCH)     // 16 chunks
#define CHB (KCH * D * 2)  // 16384 bytes per chunk

__device__ __forceinline__ void stage_chunk(const unsigned short* __restrict__ Cbf,
                                            unsigned short* buf, int chunk,
                                            int t) {
    const char* gbase = (const char*)Cbf + (size_t)chunk * CHB;
    char* lbase = (char*)buf + (t >> 6) * 1024;   // wave-uniform; HW adds lane*16
#pragma unroll
    for (int it = 0; it < CHB / 8192; it++) {     // 512 thr x 16B = 8192 B/pass
        const int a   = it * 8192 + t * 16;       // linear byte offset in chunk
        const int row = a >> 8;                   // 0..63 (256 B per row)
        const int src = (row << 8) | ((a & 255) ^ ((row & 7) << 4));
        async_copy16(gbase + src, lbase + it * 8192);
    }
}

__global__ __launch_bounds__(512, 4) void assign_kernel(
    const float* __restrict__ X,
    const unsigned short* __restrict__ Cbf,
    const float* __restrict__ CC,
    int* __restrict__ y_hat,
    float* __restrict__ inertia)
{
    __shared__ __align__(16) unsigned short Bs[2][KCH * D];  // 2 x 16 KB
    __shared__ float CCs[KC];   // 4 KB
    __shared__ float xxs[BM];   // 1 KB

    const int t    = threadIdx.x;
    const int w    = t >> 6;
    const int lane = t & 63;
    const int m16  = lane & 15;
    const int quad = lane >> 4;
    const int pbase = blockIdx.x * BM;

    for (int i = t; i < KC; i += 512) CCs[i] = CC[i];

    // kick off chunk-0 staging early: overlaps the X/afrag HBM phase
    stage_chunk(Cbf, Bs[0], 0, t);

    // ---- A fragments (bf16) + exact fp32 ||x||^2 ----
    bf16x8 afrag[MT][4];
#pragma unroll
    for (int mt = 0; mt < MT; mt++) {
        const int p = pbase + w * 32 + mt * 16 + m16;
        const float* xr = X + (size_t)p * D;
        float xp = 0.f;
#pragma unroll
        for (int ks = 0; ks < 4; ks++) {
            const int d0 = ks * 32 + quad * 8;
            float4 u0 = *(const float4*)(xr + d0);
            float4 u1 = *(const float4*)(xr + d0 + 4);
            xp = fmaf(u0.x, u0.x, xp); xp = fmaf(u0.y, u0.y, xp);
            xp = fmaf(u0.z, u0.z, xp); xp = fmaf(u0.w, u0.w, xp);
            xp = fmaf(u1.x, u1.x, xp); xp = fmaf(u1.y, u1.y, xp);
            xp = fmaf(u1.z, u1.z, xp); xp = fmaf(u1.w, u1.w, xp);
            bf16x8 f;
            f[0] = (__bf16)u0.x; f[1] = (__bf16)u0.y; f[2] = (__bf16)u0.z; f[3] = (__bf16)u0.w;
            f[4] = (__bf16)u1.x; f[5] = (__bf16)u1.y; f[6] = (__bf16)u1.z; f[7] = (__bf16)u1.w;
            afrag[mt][ks] = f;
        }
        xp += __shfl_xor(xp, 16, 64);
        xp += __shfl_xor(xp, 32, 64);
        if (quad == 0) xxs[w * 32 + mt * 16 + m16] = xp;
    }

    // packed running min: value in high bits, global step index in low 6
    float best[MT][4];
#pragma unroll
    for (int mt = 0; mt < MT; mt++)
#pragma unroll
        for (int r = 0; r < 4; r++) best[mt][r] = 3.4e38f;

    __syncthreads();   // chunk-0 staged (vmcnt drained), CCs ready

    for (int ch = 0; ch < NCH; ch++) {
        // prefetch next chunk into the other buffer (drained by end-barrier)
        if (ch + 1 < NCH) stage_chunk(Cbf, Bs[(ch + 1) & 1], ch + 1, t);

        const char* bufc = (const char*)Bs[ch & 1];
#pragma unroll
        for (int s = 0; s < KCH / 16; s++) {
            const int row  = s * 16 + m16;
            const int rswz = (row & 7) << 4;
            const char* rb = bufc + row * 256;

            floatx4 accs[MT];
#pragma unroll
            for (int mt = 0; mt < MT; mt++) accs[mt] = (floatx4){0.f, 0.f, 0.f, 0.f};

            // two half-passes of (2 ds_read + 4*MT MFMA): bounds b-frag pressure
#pragma unroll
            for (int kh = 0; kh < 2; kh++) {
                bf16x8 b0 = *(const bf16x8*)(rb + ((quad * 16 + (kh * 2 + 0) * 64) ^ rswz));
                bf16x8 b1 = *(const bf16x8*)(rb + ((quad * 16 + (kh * 2 + 1) * 64) ^ rswz));
#pragma unroll
                for (int mt = 0; mt < MT; mt++)
                    accs[mt] = __builtin_amdgcn_mfma_f32_16x16x32_bf16(
                        afrag[mt][kh * 2 + 0], b0, accs[mt], 0, 0, 0);
#pragma unroll
                for (int mt = 0; mt < MT; mt++)
                    accs[mt] = __builtin_amdgcn_mfma_f32_16x16x32_bf16(
                        afrag[mt][kh * 2 + 1], b1, accs[mt], 0, 0, 0);
            }

            const int g = ch * (KCH / 16) + s;   // global step 0..63
            const float ccv = CCs[g * 16 + m16];
#pragma unroll
            for (int mt = 0; mt < MT; mt++)
#pragma unroll
                for (int r = 0; r < 4; r++) {
                    float d2 = fmaf(-2.f, accs[mt][r], ccv);
                    unsigned ub = (__float_as_uint(d2) & ~63u) | (unsigned)g;
                    best[mt][r] = fminf(best[mt][r], __uint_as_float(ub));
                }
        }
        if (ch + 1 < NCH) __syncthreads();  // drains prefetch; protects buffer reuse
    }

    // ---- unpack + cross-lane argmin over the 16 columns + write ----
    float part = 0.f;
#pragma unroll
    for (int mt = 0; mt < MT; mt++)
#pragma unroll
        for (int r = 0; r < 4; r++) {
            const unsigned ub = __float_as_uint(best[mt][r]);
            int   k = (int)(ub & 63u) * 16 + m16;
            float b = __uint_as_float(ub & ~63u);
#pragma unroll
            for (int m = 1; m < 16; m <<= 1) {
                float ob = __shfl_xor(b, m, 64);
                int   ok = __shfl_xor(k, m, 64);
                if (ob < b || (ob == b && ok < k)) { b = ob; k = ok; }
            }
            if (m16 == 0) {
                const int row = quad * 4 + r;
                const int p = pbase + w * 32 + mt * 16 + row;
                y_hat[p] = k;
                const float xx = xxs[w * 32 + mt * 16 + row];
                part += sqrtf(fmaxf(xx + b, 0.f));
            }
        }
#pragma unroll
    for (int m = 1; m < 64; m <<= 1) part += __shfl_xor(part, m, 64);
    if (lane == 0) atomicAdd(inertia, part);
}

// ---------------- histogram: 64 blocks, LDS bins, sparse flush ----------
__global__ void hist_kernel(const int* __restrict__ y_hat, int* __restrict__ counts) {
    __shared__ int h[KC];
    for (int i = threadIdx.x; i < KC; i += 256) h[i] = 0;
    __syncthreads();
    for (int i = blockIdx.x * 256 + threadIdx.x; i < NPTS; i += gridDim.x * 256)
        atomicAdd(&h[y_hat[i]], 1);
    __syncthreads();
    for (int i = threadIdx.x; i < KC; i += 256) {
        int v = h[i];
        if (v) atomicAdd(&counts[i], v);
    }
}

// ---------------- exclusive scan ----------------
__global__ void scan_kernel(const int* __restrict__ counts, int* __restrict__ cursor) {
    __shared__ int tmp[KC];
    int t = threadIdx.x;
    tmp[t] = counts[t];
    __syncthreads();
    for (int off = 1; off < KC; off <<= 1) {
        int v = tmp[t];
        int add = (t >= off) ? tmp[t - off] : 0;
        __syncthreads();
        tmp[t] = v + add;
        __syncthreads();
    }
    cursor[t] = (t == 0) ? 0 : tmp[t - 1];
}

// ---------------- scatter: LDS-rank, one cursor bump per (block,bin) -----
#define SPB 2048   // points per scatter block
__global__ __launch_bounds__(256) void scatter_kernel(
    const int* __restrict__ y_hat,
    int* __restrict__ cursor,
    int* __restrict__ order)
{
    __shared__ int h[KC];
    const int t = threadIdx.x;
    const int base_i = blockIdx.x * SPB;
    for (int i = t; i < KC; i += 256) h[i] = 0;
    __syncthreads();
    int myk[SPB / 256], myr[SPB / 256];
#pragma unroll
    for (int j = 0; j < SPB / 256; j++) {
        int k = y_hat[base_i + j * 256 + t];
        myk[j] = k;
        myr[j] = atomicAdd(&h[k], 1);
    }
    __syncthreads();
    for (int b = t; b < KC; b += 256) {
        int c = h[b];
        if (c) h[b] = atomicAdd(&cursor[b], c);   // reuse h[] as base[]
    }
    __syncthreads();
#pragma unroll
    for (int j = 0; j < SPB / 256; j++)
        order[h[myk[j]] + myr[j]] = base_i + j * 256 + t;
}

// ---------------- segmented reduction: depth-4 prefetch ----------------
#define PPB 256
__global__ __launch_bounds__(256) void segsum_kernel(
    const float* __restrict__ X, const float* __restrict__ W,
    const int* __restrict__ order, const int* __restrict__ y_hat,
    float* __restrict__ w_sum, float* __restrict__ xw_sum)
{
    __shared__ int ps[PPB];
    __shared__ int kk[PPB];
    const int t = threadIdx.x;
    const int i0 = blockIdx.x * PPB;
    {
        int p = order[i0 + t];
        ps[t] = p;
        kk[t] = y_hat[p];
    }
    __syncthreads();

    const int d = t & 127;
    const int g = t >> 7;    // half: points g, g+2, ...

    float xs[4], wv[4];
#pragma unroll
    for (int j = 0; j < 4; j++) {
        int p = ps[g + 2 * j];
        xs[j] = X[(size_t)p * D + d];
        wv[j] = W[(size_t)p * D + d];
    }

    float wacc = 0.f, xwacc = 0.f;
    int cur = -1;

#pragma unroll 4
    for (int i = g; i < PPB; i += 2) {
        float xn = 0.f, wn = 0.f;
        if (i + 8 < PPB) {
            int p = ps[i + 8];
            xn = X[(size_t)p * D + d];
            wn = W[(size_t)p * D + d];
        }
        int k = kk[i];
        if (k != cur) {
            if (cur >= 0) {
                atomicAdd(&w_sum[(size_t)cur * D + d], wacc);
                atomicAdd(&xw_sum[(size_t)cur * D + d], xwacc);
            }
            cur = k; wacc = 0.f; xwacc = 0.f;
        }
        wacc += wv[0];
        xwacc = fmaf(xs[0], wv[0], xwacc);
        xs[0] = xs[1]; xs[1] = xs[2]; xs[2] = xs[3]; xs[3] = xn;
        wv[0] = wv[1]; wv[1] = wv[2]; wv[2] = wv[3]; wv[3] = wn;
    }
    if (cur >= 0) {
        atomicAdd(&w_sum[(size_t)cur * D + d], wacc);
        atomicAdd(&xw_sum[(size_t)cur * D + d], xwacc);
    }
}

extern "C" void kernel_launch(void* const* d_in, const int* in_sizes, int n_in,
                              void* d_out, int out_size, void* d_ws, size_t ws_size,
                              hipStream_t stream) {
    const float* X = (const float*)d_in[0];
    const float* W = (const float*)d_in[1];
    const float* C = (const float*)d_in[2];

    float* out     = (float*)d_out;
    float* inertia = out;
    float* w_sum   = out + 1;
    float* xw_sum  = out + 1 + KC * D;

    int*   y_hat  = (int*)d_ws;
    int*   order  = y_hat + NPTS;
    int*   counts = order + NPTS;
    int*   cursor = counts + KC;
    float* CC     = (float*)(cursor + KC);
    unsigned short* Cbf = (unsigned short*)(CC + KC);   // 1024*128 bf16, 16B-aligned

    hipMemsetAsync(d_out, 0, (size_t)out_size * sizeof(float), stream);
    hipMemsetAsync(counts, 0, KC * sizeof(int), stream);

    cc_kernel<<<KC, 64, 0, stream>>>(C, CC, Cbf);
    assign_kernel<<<NPTS / BM, 512, 0, stream>>>(X, Cbf, CC, y_hat, inertia);
    hist_kernel<<<64, 256, 0, stream>>>(y_hat, counts);
    scan_kernel<<<1, KC, 0, stream>>>(counts, cursor);
    scatter_kernel<<<NPTS / SPB, 256, 0, stream>>>(y_hat, cursor, order);
    segsum_kernel<<<NPTS / PPB, 256, 0, stream>>>(X, W, order, y_hat, w_sum, xw_sum);
}

// Round 7
// 402.272 us; speedup vs baseline: 1.2621x; 1.1212x over previous
//
#include <hip/hip_runtime.h>
#include <math.h>

#define NPTS 262144
#define D 128
#define KC 1024

typedef __bf16 bf16x8 __attribute__((ext_vector_type(8)));
typedef float floatx4 __attribute__((ext_vector_type(4)));

// async global->LDS, 16B per lane. LDS dest must be wave-uniform base (+lane*16 in HW).
__device__ __forceinline__ void async_copy16(const void* g, void* l) {
    __builtin_amdgcn_global_load_lds(
        (const __attribute__((address_space(1))) void*)g,
        (__attribute__((address_space(3))) void*)l, 16, 0, 0);
}

// ---------------- centroid norms + bf16 convert ----------------
__global__ void cc_kernel(const float* __restrict__ C, float* __restrict__ CC,
                          unsigned short* __restrict__ Cbf) {
    const int row  = blockIdx.x;
    const int lane = threadIdx.x;
    float2 v = *(const float2*)(C + (size_t)row * D + lane * 2);
    __bf16 b0 = (__bf16)v.x, b1 = (__bf16)v.y;
    unsigned short u0, u1;
    __builtin_memcpy(&u0, &b0, 2);
    __builtin_memcpy(&u1, &b1, 2);
    ((ushort2*)Cbf)[(size_t)row * 64 + lane] = make_ushort2(u0, u1);
    float s = fmaf(v.x, v.x, v.y * v.y);
#pragma unroll
    for (int m = 1; m < 64; m <<= 1) s += __shfl_xor(s, m, 64);
    if (lane == 0) CC[row] = s;
}

// ---------------- assignment: LDS-staged bf16 MFMA + packed argmin ------
// 256 thr = 4 waves, BM=256 pts/block, mt=4 (64 pts/wave). Round-6 A/B
// proved mt=4 is the right per-wave structure (mt=2 halved MFMA-per-
// ds_read latency cover: 210us vs 142us at HIGHER occupancy).
// Occupancy ladder on this structure:
//   (256,2): compiler allocs >170 total regs (arch 84 + AGPRs) -> 2 w/SIMD, 142us
//   (256,4): 128-reg budget < ~140 live set -> spills (FETCH 270MB), 245us
//   (256,3): 170-reg budget >= ~140 live -> 3 w/SIMD, no spill  <- THIS
// Tripwire: FETCH_SIZE >> 68 MB => spilled => (256,2) is final.
#define BM 256
#define KCH 64             // centroids per LDS chunk
#define NCH (KC / KCH)     // 16 chunks
#define CHB (KCH * D * 2)  // 16384 bytes per chunk

__device__ __forceinline__ void stage_chunk(const unsigned short* __restrict__ Cbf,
                                            unsigned short* buf, int chunk,
                                            int t, int w) {
    const char* gbase = (const char*)Cbf + (size_t)chunk * CHB;
    char* lbase = (char*)buf + w * 1024;   // wave-uniform; HW adds lane*16
#pragma unroll
    for (int it = 0; it < CHB / 4096; it++) {
        const int a   = it * 4096 + t * 16;     // linear byte offset in chunk
        const int row = a >> 8;                 // 0..63 (256 B per row)
        const int src = (row << 8) | ((a & 255) ^ ((row & 7) << 4));
        async_copy16(gbase + src, lbase + it * 4096);
    }
}

__global__ __launch_bounds__(256, 3) void assign_kernel(
    const float* __restrict__ X,
    const unsigned short* __restrict__ Cbf,
    const float* __restrict__ CC,
    int* __restrict__ y_hat,
    float* __restrict__ inertia)
{
    __shared__ __align__(16) unsigned short Bs[2][KCH * D];  // 2 x 16 KB
    __shared__ float CCs[KC];   // 4 KB
    __shared__ float xxs[BM];   // 1 KB

    const int t    = threadIdx.x;
    const int w    = t >> 6;
    const int lane = t & 63;
    const int m16  = lane & 15;
    const int quad = lane >> 4;
    const int pbase = blockIdx.x * BM;

    for (int i = t; i < KC; i += 256) CCs[i] = CC[i];

    // kick off chunk-0 staging early: overlaps the X/afrag HBM phase
    stage_chunk(Cbf, Bs[0], 0, t, w);

    // ---- A fragments (bf16) + exact fp32 ||x||^2 ----
    bf16x8 afrag[4][4];
#pragma unroll
    for (int mt = 0; mt < 4; mt++) {
        const int p = pbase + w * 64 + mt * 16 + m16;
        const float* xr = X + (size_t)p * D;
        float xp = 0.f;
#pragma unroll
        for (int ks = 0; ks < 4; ks++) {
            const int d0 = ks * 32 + quad * 8;
            float4 u0 = *(const float4*)(xr + d0);
            float4 u1 = *(const float4*)(xr + d0 + 4);
            xp = fmaf(u0.x, u0.x, xp); xp = fmaf(u0.y, u0.y, xp);
            xp = fmaf(u0.z, u0.z, xp); xp = fmaf(u0.w, u0.w, xp);
            xp = fmaf(u1.x, u1.x, xp); xp = fmaf(u1.y, u1.y, xp);
            xp = fmaf(u1.z, u1.z, xp); xp = fmaf(u1.w, u1.w, xp);
            bf16x8 f;
            f[0] = (__bf16)u0.x; f[1] = (__bf16)u0.y; f[2] = (__bf16)u0.z; f[3] = (__bf16)u0.w;
            f[4] = (__bf16)u1.x; f[5] = (__bf16)u1.y; f[6] = (__bf16)u1.z; f[7] = (__bf16)u1.w;
            afrag[mt][ks] = f;
        }
        xp += __shfl_xor(xp, 16, 64);
        xp += __shfl_xor(xp, 32, 64);
        if (quad == 0) xxs[w * 64 + mt * 16 + m16] = xp;
    }

    // packed running min: value in high bits, global step index in low 6
    float best[4][4];
#pragma unroll
    for (int mt = 0; mt < 4; mt++)
#pragma unroll
        for (int r = 0; r < 4; r++) best[mt][r] = 3.4e38f;

    __syncthreads();   // chunk-0 staged (vmcnt drained), CCs ready

    for (int ch = 0; ch < NCH; ch++) {
        // prefetch next chunk into the other buffer (drained by end-barrier)
        if (ch + 1 < NCH) stage_chunk(Cbf, Bs[(ch + 1) & 1], ch + 1, t, w);

        const char* bufc = (const char*)Bs[ch & 1];
#pragma unroll
        for (int s = 0; s < KCH / 16; s++) {
            const int row  = s * 16 + m16;
            const int rswz = (row & 7) << 4;
            const char* rb = bufc + row * 256;

            floatx4 accs[4];
#pragma unroll
            for (int mt = 0; mt < 4; mt++) accs[mt] = (floatx4){0.f, 0.f, 0.f, 0.f};

            // two half-passes of (2 ds_read + 8 MFMA): bounds b-frag pressure
#pragma unroll
            for (int kh = 0; kh < 2; kh++) {
                bf16x8 b0 = *(const bf16x8*)(rb + ((quad * 16 + (kh * 2 + 0) * 64) ^ rswz));
                bf16x8 b1 = *(const bf16x8*)(rb + ((quad * 16 + (kh * 2 + 1) * 64) ^ rswz));
#pragma unroll
                for (int mt = 0; mt < 4; mt++)
                    accs[mt] = __builtin_amdgcn_mfma_f32_16x16x32_bf16(
                        afrag[mt][kh * 2 + 0], b0, accs[mt], 0, 0, 0);
#pragma unroll
                for (int mt = 0; mt < 4; mt++)
                    accs[mt] = __builtin_amdgcn_mfma_f32_16x16x32_bf16(
                        afrag[mt][kh * 2 + 1], b1, accs[mt], 0, 0, 0);
            }

            const int g = ch * (KCH / 16) + s;   // global step 0..63
            const float ccv = CCs[g * 16 + m16];
#pragma unroll
            for (int mt = 0; mt < 4; mt++)
#pragma unroll
                for (int r = 0; r < 4; r++) {
                    float d2 = fmaf(-2.f, accs[mt][r], ccv);
                    unsigned ub = (__float_as_uint(d2) & ~63u) | (unsigned)g;
                    best[mt][r] = fminf(best[mt][r], __uint_as_float(ub));
                }
        }
        if (ch + 1 < NCH) __syncthreads();  // drains prefetch; protects buffer reuse
    }

    // ---- unpack + cross-lane argmin over the 16 columns + write ----
    float part = 0.f;
#pragma unroll
    for (int mt = 0; mt < 4; mt++)
#pragma unroll
        for (int r = 0; r < 4; r++) {
            const unsigned ub = __float_as_uint(best[mt][r]);
            int   k = (int)(ub & 63u) * 16 + m16;
            float b = __uint_as_float(ub & ~63u);
#pragma unroll
            for (int m = 1; m < 16; m <<= 1) {
                float ob = __shfl_xor(b, m, 64);
                int   ok = __shfl_xor(k, m, 64);
                if (ob < b || (ob == b && ok < k)) { b = ob; k = ok; }
            }
            if (m16 == 0) {
                const int row = quad * 4 + r;
                const int p = pbase + w * 64 + mt * 16 + row;
                y_hat[p] = k;
                const float xx = xxs[w * 64 + mt * 16 + row];
                part += sqrtf(fmaxf(xx + b, 0.f));
            }
        }
#pragma unroll
    for (int m = 1; m < 64; m <<= 1) part += __shfl_xor(part, m, 64);
    if (lane == 0) atomicAdd(inertia, part);
}

// ---------------- histogram: 64 blocks, LDS bins, sparse flush ----------
__global__ void hist_kernel(const int* __restrict__ y_hat, int* __restrict__ counts) {
    __shared__ int h[KC];
    for (int i = threadIdx.x; i < KC; i += 256) h[i] = 0;
    __syncthreads();
    for (int i = blockIdx.x * 256 + threadIdx.x; i < NPTS; i += gridDim.x * 256)
        atomicAdd(&h[y_hat[i]], 1);
    __syncthreads();
    for (int i = threadIdx.x; i < KC; i += 256) {
        int v = h[i];
        if (v) atomicAdd(&counts[i], v);
    }
}

// ---------------- exclusive scan ----------------
__global__ void scan_kernel(const int* __restrict__ counts, int* __restrict__ cursor) {
    __shared__ int tmp[KC];
    int t = threadIdx.x;
    tmp[t] = counts[t];
    __syncthreads();
    for (int off = 1; off < KC; off <<= 1) {
        int v = tmp[t];
        int add = (t >= off) ? tmp[t - off] : 0;
        __syncthreads();
        tmp[t] = v + add;
        __syncthreads();
    }
    cursor[t] = (t == 0) ? 0 : tmp[t - 1];
}

// ---------------- scatter: LDS-rank, one cursor bump per (block,bin) -----
#define SPB 2048   // points per scatter block
__global__ __launch_bounds__(256) void scatter_kernel(
    const int* __restrict__ y_hat,
    int* __restrict__ cursor,
    int* __restrict__ order)
{
    __shared__ int h[KC];
    const int t = threadIdx.x;
    const int base_i = blockIdx.x * SPB;
    for (int i = t; i < KC; i += 256) h[i] = 0;
    __syncthreads();
    int myk[SPB / 256], myr[SPB / 256];
#pragma unroll
    for (int j = 0; j < SPB / 256; j++) {
        int k = y_hat[base_i + j * 256 + t];
        myk[j] = k;
        myr[j] = atomicAdd(&h[k], 1);
    }
    __syncthreads();
    for (int b = t; b < KC; b += 256) {
        int c = h[b];
        if (c) h[b] = atomicAdd(&cursor[b], c);   // reuse h[] as base[]
    }
    __syncthreads();
#pragma unroll
    for (int j = 0; j < SPB / 256; j++)
        order[h[myk[j]] + myr[j]] = base_i + j * 256 + t;
}

// ---------------- segmented reduction: depth-4 prefetch ----------------
#define PPB 256
__global__ __launch_bounds__(256) void segsum_kernel(
    const float* __restrict__ X, const float* __restrict__ W,
    const int* __restrict__ order, const int* __restrict__ y_hat,
    float* __restrict__ w_sum, float* __restrict__ xw_sum)
{
    __shared__ int ps[PPB];
    __shared__ int kk[PPB];
    const int t = threadIdx.x;
    const int i0 = blockIdx.x * PPB;
    {
        int p = order[i0 + t];
        ps[t] = p;
        kk[t] = y_hat[p];
    }
    __syncthreads();

    const int d = t & 127;
    const int g = t >> 7;    // half: points g, g+2, ...

    float xs[4], wv[4];
#pragma unroll
    for (int j = 0; j < 4; j++) {
        int p = ps[g + 2 * j];
        xs[j] = X[(size_t)p * D + d];
        wv[j] = W[(size_t)p * D + d];
    }

    float wacc = 0.f, xwacc = 0.f;
    int cur = -1;

#pragma unroll 4
    for (int i = g; i < PPB; i += 2) {
        float xn = 0.f, wn = 0.f;
        if (i + 8 < PPB) {
            int p = ps[i + 8];
            xn = X[(size_t)p * D + d];
            wn = W[(size_t)p * D + d];
        }
        int k = kk[i];
        if (k != cur) {
            if (cur >= 0) {
                atomicAdd(&w_sum[(size_t)cur * D + d], wacc);
                atomicAdd(&xw_sum[(size_t)cur * D + d], xwacc);
            }
            cur = k; wacc = 0.f; xwacc = 0.f;
        }
        wacc += wv[0];
        xwacc = fmaf(xs[0], wv[0], xwacc);
        xs[0] = xs[1]; xs[1] = xs[2]; xs[2] = xs[3]; xs[3] = xn;
        wv[0] = wv[1]; wv[1] = wv[2]; wv[2] = wv[3]; wv[3] = wn;
    }
    if (cur >= 0) {
        atomicAdd(&w_sum[(size_t)cur * D + d], wacc);
        atomicAdd(&xw_sum[(size_t)cur * D + d], xwacc);
    }
}

extern "C" void kernel_launch(void* const* d_in, const int* in_sizes, int n_in,
                              void* d_out, int out_size, void* d_ws, size_t ws_size,
                              hipStream_t stream) {
    const float* X = (const float*)d_in[0];
    const float* W = (const float*)d_in[1];
    const float* C = (const float*)d_in[2];

    float* out     = (float*)d_out;
    float* inertia = out;
    float* w_sum   = out + 1;
    float* xw_sum  = out + 1 + KC * D;

    int*   y_hat  = (int*)d_ws;
    int*   order  = y_hat + NPTS;
    int*   counts = order + NPTS;
    int*   cursor = counts + KC;
    float* CC     = (float*)(cursor + KC);
    unsigned short* Cbf = (unsigned short*)(CC + KC);   // 1024*128 bf16, 16B-aligned

    hipMemsetAsync(d_out, 0, (size_t)out_size * sizeof(float), stream);
    hipMemsetAsync(counts, 0, KC * sizeof(int), stream);

    cc_kernel<<<KC, 64, 0, stream>>>(C, CC, Cbf);
    assign_kernel<<<NPTS / BM, 256, 0, stream>>>(X, Cbf, CC, y_hat, inertia);
    hist_kernel<<<64, 256, 0, stream>>>(y_hat, counts);
    scan_kernel<<<1, KC, 0, stream>>>(counts, cursor);
    scatter_kernel<<<NPTS / SPB, 256, 0, stream>>>(y_hat, cursor, order);
    segsum_kernel<<<NPTS / PPB, 256, 0, stream>>>(X, W, order, y_hat, w_sum, xw_sum);
}